// Round 13
// baseline (1025.641 us; speedup 1.0000x reference)
//
#include <hip/hip_runtime.h>
#include <hip/hip_bf16.h>
#include <math.h>

// Problem dims (fixed)
#define BATCHN   4
#define CHN      8
#define SEQ      1024
#define DMODEL   512
#define DSTATE   16
#define DCONV    4
#define DINNER   1024
#define DTRANK   32
#define NROWS    32768          // BATCH*CH*SEQ
#define XD       64             // DT_RANK + 2*D_STATE
#define NBC      32             // BATCH*CH (independent sequences)

// Scan chunking
#define GCH   16                // chunks per sequence
#define CLEN  (SEQ / GCH)       // 64 timesteps per chunk
#define PSLOT 17                // ps slots per (chunk,b,d): [dtsum | S x16]

// Conv splitting
#define CSPL  8                 // t-splits per sequence
#define CTS   (SEQ / CSPL)      // 128 timesteps per split

enum { EPI_NONE = 0, EPI_GATE = 1, EPI_GATE_PACK = 2 };

__device__ __forceinline__ float siluf(float v) {
    return v / (1.0f + __expf(-v));   // hw v_exp (~3 ops) vs library expf (~25)
}
__device__ __forceinline__ float softplus_fast(float v) {
    return (v > 20.0f) ? v : __logf(1.0f + __expf(v));
}

typedef short short8 __attribute__((ext_vector_type(8)));
typedef float floatx4 __attribute__((ext_vector_type(4)));

__device__ __forceinline__ unsigned short f2bf_rne(float f) {
    unsigned int u = __float_as_uint(f);
    u += 0x7fffu + ((u >> 16) & 1u);
    return (unsigned short)(u >> 16);
}
__device__ __forceinline__ float bf2f(unsigned short h) {
    return __uint_as_float(((unsigned int)h) << 16);
}

// LDS tile addressing (BK=32 arrays, 32-short rows): 4 x 16-B slots per row,
// slot XOR-swizzled by (row>>1)&3. Same mapping on store and read.
__device__ __forceinline__ unsigned short* lds_pt(unsigned short (*arr)[32],
                                                  int row, int slot) {
    return &arr[row][(slot ^ ((row >> 1) & 3)) << 3];
}
__device__ __forceinline__ const unsigned short* lds_pt(
        const unsigned short (*arr)[32], int row, int slot) {
    return &arr[row][(slot ^ ((row >> 1) & 3)) << 3];
}

// BK=64 arrays: 64-short rows (128 B = exactly 32 banks), 8 x 16-B slots,
// slot XOR-swizzled by row&7. Per 8-lane phase group both stores and
// fragment reads cover 8 distinct physical slots -> conflict-free.
__device__ __forceinline__ unsigned short* lds_pt8(unsigned short (*arr)[64],
                                                   int row, int slot) {
    return &arr[row][(slot ^ (row & 7)) << 3];
}
__device__ __forceinline__ const unsigned short* lds_pt8(
        const unsigned short (*arr)[64], int row, int slot) {
    return &arr[row][(slot ^ (row & 7)) << 3];
}

// ---------------- prepass: f32 [R][K] -> blocked split bf16 --------------------
// Per (row, kblock of 32 k's): 128 B = [32 x hi bf16 | 32 x lo bf16], linear.
// hi+lo pairs are bit-identical to the GEMM's on-the-fly split (same f2bf_rne).
__global__ __launch_bounds__(256)
void split_w(const float* __restrict__ W, unsigned char* __restrict__ W2,
             int R, int K) {
    const int KB = K >> 5;
    const int idx = blockIdx.x * 256 + threadIdx.x;   // one per (row, kblock)
    if (idx >= R * KB) return;
    const int row = idx / KB;
    const int kb  = idx - row * KB;
    const float* src = W + (size_t)row * K + kb * 32;
    unsigned short h[32], l[32];
#pragma unroll
    for (int e = 0; e < 32; e += 4) {
        const float4 v = *(const float4*)(src + e);
        const float vv[4] = {v.x, v.y, v.z, v.w};
#pragma unroll
        for (int q = 0; q < 4; ++q) {
            const unsigned short hi = f2bf_rne(vv[q]);
            h[e + q] = hi;
            l[e + q] = f2bf_rne(vv[q] - bf2f(hi));
        }
    }
    unsigned char* dst = W2 + ((size_t)row * KB + kb) * 128;
    union { short8 v; unsigned short u[8]; } pk;
#pragma unroll
    for (int c = 0; c < 4; ++c) {           // hi bytes [0,64)
#pragma unroll
        for (int e = 0; e < 8; ++e) pk.u[e] = h[c * 8 + e];
        *(short8*)(dst + c * 16) = pk.v;
    }
#pragma unroll
    for (int c = 0; c < 4; ++c) {           // lo bytes [64,128)
#pragma unroll
        for (int e = 0; e < 8; ++e) pk.u[e] = l[c * 8 + e];
        *(short8*)(dst + 64 + c * 16) = pk.v;
    }
}

// ---------------- bf16-split MFMA GEMM: C[M,N] = A[M,K] * B[N,K]^T --------------
// 3-term split product hi*hi + lo*hi + hi*lo in fp32 accumulators (~2^-17 rel).
// BK=64: two 32-k blocks staged per barrier pair -> barrier count halves
// (the vmcnt(0)+lgkmcnt(0) drain before each s_barrier is the structural
// stall; MfmaUtil ~20-30%). 96 MFMAs/wave per iteration. LDS 64 KiB ->
// 2 blocks/CU (128 <= 160 KiB). Accumulation order per (i,j) unchanged
// (kb ascending) -> bit-identical C.
// A_PRE / B_PRE: operand pre-split blocked bf16 -> staging is pure short8
// load + LDS store, zero conversion VALU. Otherwise f32 split on the fly.
// EPI_GATE:      C = C_old * silu(acc)  (f32 write)
// EPI_GATE_PACK: g = C_old * silu(acc); write g as blocked hi/lo bf16 IN PLACE
//   over C. Safe: each 128-B block read+written by exactly one wave quad;
//   reads hoisted per row-group + vmcnt(0) fence before stores.
template <bool A_PRE, bool B_PRE, int EPI>
__global__ __launch_bounds__(256, 2)
void gemm_split(const float* __restrict__ Af, const unsigned char* __restrict__ A2,
                int lda,
                const float* __restrict__ Bf, const unsigned char* __restrict__ B2,
                int ldb,
                float* __restrict__ C, int ldc,
                int K) {
    __shared__ __align__(16) unsigned short Ah[128][64];
    __shared__ __align__(16) unsigned short Al[128][64];
    __shared__ __align__(16) unsigned short Bh[128][64];
    __shared__ __align__(16) unsigned short Bl[128][64];

    const int tid  = threadIdx.x;
    const int lane = tid & 63;
    const int wv   = tid >> 6;
    const int quad = lane >> 4;
    const int m16  = lane & 15;
    const int wm   = (wv & 1) * 64;       // wave's m-offset in block tile
    const int wn   = (wv >> 1) * 64;      // wave's n-offset
    const int m0   = blockIdx.y * 128;
    const int n0   = blockIdx.x * 128;
    const int KB   = K >> 5;

    const int srow = tid >> 1;            // staging row 0..127
    const int hh   = tid & 1;             // staging k-half 0/1 (32 k's each)

    const unsigned char* aptr = nullptr;
    const unsigned char* bptr = nullptr;
    if constexpr (A_PRE)
        aptr = A2 + (size_t)(m0 + srow) * KB * 128 + (size_t)hh * 128;
    if constexpr (B_PRE)
        bptr = B2 + (size_t)(n0 + srow) * KB * 128 + (size_t)hh * 128;

    floatx4 acc[4][4];
#pragma unroll
    for (int i = 0; i < 4; ++i)
#pragma unroll
        for (int j = 0; j < 4; ++j) acc[i][j] = (floatx4){0.f, 0.f, 0.f, 0.f};

    union U { short8 v; unsigned short u[8]; };

    for (int k0 = 0; k0 < K; k0 += 64) {
        short8 pah[4], pal[4];             // this thread's A-half (hi/lo, 64 B)
        short8 pbh[4], pbl[4];
        if constexpr (A_PRE) {
            pah[0] = *(const short8*)(aptr + 0);
            pah[1] = *(const short8*)(aptr + 16);
            pah[2] = *(const short8*)(aptr + 32);
            pah[3] = *(const short8*)(aptr + 48);
            pal[0] = *(const short8*)(aptr + 64);
            pal[1] = *(const short8*)(aptr + 80);
            pal[2] = *(const short8*)(aptr + 96);
            pal[3] = *(const short8*)(aptr + 112);
            aptr += 256;
        } else {
            const float* ap = Af + (size_t)(m0 + srow) * lda + k0 + hh * 32;
#pragma unroll
            for (int c = 0; c < 4; ++c) {
                const float4 v0 = *(const float4*)(ap + c * 8);
                const float4 v1 = *(const float4*)(ap + c * 8 + 4);
                const float vv[8] = {v0.x, v0.y, v0.z, v0.w,
                                     v1.x, v1.y, v1.z, v1.w};
                U uh, ul;
#pragma unroll
                for (int e = 0; e < 8; ++e) {
                    const unsigned short hi = f2bf_rne(vv[e]);
                    uh.u[e] = hi; ul.u[e] = f2bf_rne(vv[e] - bf2f(hi));
                }
                pah[c] = uh.v; pal[c] = ul.v;
            }
        }
        if constexpr (B_PRE) {
            pbh[0] = *(const short8*)(bptr + 0);
            pbh[1] = *(const short8*)(bptr + 16);
            pbh[2] = *(const short8*)(bptr + 32);
            pbh[3] = *(const short8*)(bptr + 48);
            pbl[0] = *(const short8*)(bptr + 64);
            pbl[1] = *(const short8*)(bptr + 80);
            pbl[2] = *(const short8*)(bptr + 96);
            pbl[3] = *(const short8*)(bptr + 112);
            bptr += 256;
        } else {
            const float* bp = Bf + (size_t)(n0 + srow) * ldb + k0 + hh * 32;
#pragma unroll
            for (int c = 0; c < 4; ++c) {
                const float4 v0 = *(const float4*)(bp + c * 8);
                const float4 v1 = *(const float4*)(bp + c * 8 + 4);
                const float vv[8] = {v0.x, v0.y, v0.z, v0.w,
                                     v1.x, v1.y, v1.z, v1.w};
                U uh, ul;
#pragma unroll
                for (int e = 0; e < 8; ++e) {
                    const unsigned short hi = f2bf_rne(vv[e]);
                    uh.u[e] = hi; ul.u[e] = f2bf_rne(vv[e] - bf2f(hi));
                }
                pbh[c] = uh.v; pbl[c] = ul.v;
            }
        }

        __syncthreads();   // all waves done reading previous tile
#pragma unroll
        for (int c = 0; c < 4; ++c) {
            const int sl = 4 * hh + c;    // logical slot 0..7
            *(short8*)lds_pt8(Ah, srow, sl) = pah[c];
            *(short8*)lds_pt8(Al, srow, sl) = pal[c];
            *(short8*)lds_pt8(Bh, srow, sl) = pbh[c];
            *(short8*)lds_pt8(Bl, srow, sl) = pbl[c];
        }
        __syncthreads();

#pragma unroll
        for (int kk = 0; kk < 2; ++kk) {
            short8 a_h[4], a_l[4], b_h[4], b_l[4];
            const int sl = 4 * kk + quad;
#pragma unroll
            for (int i = 0; i < 4; ++i) {
                a_h[i] = *(const short8*)lds_pt8(Ah, wm + i * 16 + m16, sl);
                a_l[i] = *(const short8*)lds_pt8(Al, wm + i * 16 + m16, sl);
                b_h[i] = *(const short8*)lds_pt8(Bh, wn + i * 16 + m16, sl);
                b_l[i] = *(const short8*)lds_pt8(Bl, wn + i * 16 + m16, sl);
            }
#pragma unroll
            for (int i = 0; i < 4; ++i)
#pragma unroll
                for (int j = 0; j < 4; ++j) {
                    acc[i][j] = __builtin_amdgcn_mfma_f32_16x16x32_bf16(
                        a_h[i], b_h[j], acc[i][j], 0, 0, 0);
                    acc[i][j] = __builtin_amdgcn_mfma_f32_16x16x32_bf16(
                        a_l[i], b_h[j], acc[i][j], 0, 0, 0);
                    acc[i][j] = __builtin_amdgcn_mfma_f32_16x16x32_bf16(
                        a_h[i], b_l[j], acc[i][j], 0, 0, 0);
                }
        }
    }

    // Epilogue. C/D layout: col = lane&15, row = quad*4 + reg [m89/m91 verified]
    if constexpr (EPI != EPI_GATE_PACK) {
#pragma unroll
        for (int i = 0; i < 4; ++i)
#pragma unroll
            for (int j = 0; j < 4; ++j) {
                const int col = n0 + wn + j * 16 + m16;
#pragma unroll
                for (int r = 0; r < 4; ++r) {
                    const int row = m0 + wm + i * 16 + quad * 4 + r;
                    const size_t off = (size_t)row * ldc + col;
                    const float v = acc[i][j][r];
                    if (EPI == EPI_NONE) C[off] = v;
                    else                 C[off] = C[off] * siluf(v);
                }
            }
    } else {   // EPI_GATE_PACK: in-place f32 -> gated blocked hi/lo bf16
        unsigned char* Y2 = (unsigned char*)C;
        const size_t rowbytes = (size_t)ldc * 4;   // == (ldc/32)*128
#pragma unroll
        for (int i = 0; i < 4; ++i) {
            const int rbase = m0 + wm + i * 16 + quad * 4;
            float cold[4][4];
#pragma unroll
            for (int j = 0; j < 4; ++j) {
                const int col = n0 + wn + j * 16 + m16;
#pragma unroll
                for (int r = 0; r < 4; ++r)
                    cold[j][r] = C[(size_t)(rbase + r) * ldc + col];
            }
            // all reads of this row-group land before any byte is overwritten
            asm volatile("s_waitcnt vmcnt(0)" ::: "memory");
#pragma unroll
            for (int j = 0; j < 4; ++j) {
                const int col = n0 + wn + j * 16 + m16;
                const int kb  = col >> 5;
                const unsigned off = (unsigned)(col & 31) * 2;
#pragma unroll
                for (int r = 0; r < 4; ++r) {
                    const int row = rbase + r;
                    const float g = cold[j][r] * siluf(acc[i][j][r]);
                    const unsigned short hi = f2bf_rne(g);
                    const unsigned short lo = f2bf_rne(g - bf2f(hi));
                    unsigned char* bp = Y2 + (size_t)row * rowbytes + (size_t)kb * 128;
                    *(unsigned short*)(bp + off)      = hi;
                    *(unsigned short*)(bp + 64 + off) = lo;
                }
            }
        }
    }
}

// ---------------- MFMA x-proj GEMM: C[M,64] = A[M,K] * B[64,K]^T ---------------
// Block tile 128x64, 4 waves (2x2), each wave 64x32 = 4x2 frags,
// 24 MFMA/wave/K-step. A = xs f32 split on the fly; B = W_xproj pre-split.
// (kept at BK=32 -- verified)
__global__ __launch_bounds__(256, 2)
void gemm_xproj(const float* __restrict__ A, int lda,
                const unsigned char* __restrict__ B2,
                float* __restrict__ C, int ldc,
                int K) {
    __shared__ __align__(16) unsigned short Ah[128][32];
    __shared__ __align__(16) unsigned short Al[128][32];
    __shared__ __align__(16) unsigned short Bh[64][32];
    __shared__ __align__(16) unsigned short Bl[64][32];

    const int tid  = threadIdx.x;
    const int lane = tid & 63;
    const int wv   = tid >> 6;
    const int quad = lane >> 4;
    const int m16  = lane & 15;
    const int wm   = (wv & 1) * 64;
    const int wn   = (wv >> 1) * 32;
    const int m0   = blockIdx.x * 128;

    const int srow = tid >> 1;            // A staging row 0..127
    const int skb  = (tid & 1) * 16;
    const int ssl  = skb >> 3;

    const unsigned char* bptr = B2 + (size_t)srow * (K >> 5) * 128 + 2 * skb;
    const bool bstage = tid < 128;        // rows 0..63 (waves 0,1 only)

    floatx4 acc[4][2];
#pragma unroll
    for (int i = 0; i < 4; ++i)
#pragma unroll
        for (int j = 0; j < 2; ++j) acc[i][j] = (floatx4){0.f, 0.f, 0.f, 0.f};

    union U { short8 v; unsigned short u[8]; };

    for (int k0 = 0; k0 < K; k0 += 32) {
        const float* ap = A + (size_t)(m0 + srow) * lda + k0 + skb;
        const float4 a0 = *(const float4*)(ap + 0);
        const float4 a1 = *(const float4*)(ap + 4);
        const float4 a2 = *(const float4*)(ap + 8);
        const float4 a3 = *(const float4*)(ap + 12);
        const float af[16] = {a0.x, a0.y, a0.z, a0.w, a1.x, a1.y, a1.z, a1.w,
                              a2.x, a2.y, a2.z, a2.w, a3.x, a3.y, a3.z, a3.w};
        short8 pb0, pb1, pb2, pb3;
        if (bstage) {
            pb0 = *(const short8*)(bptr);
            pb1 = *(const short8*)(bptr + 16);
            pb2 = *(const short8*)(bptr + 64);
            pb3 = *(const short8*)(bptr + 80);
        }
        bptr += 128;

        U ah0, ah1, al0, al1;
#pragma unroll
        for (int e = 0; e < 8; ++e) {
            const unsigned short ha = f2bf_rne(af[e]);
            ah0.u[e] = ha; al0.u[e] = f2bf_rne(af[e] - bf2f(ha));
            const unsigned short hb = f2bf_rne(af[8 + e]);
            ah1.u[e] = hb; al1.u[e] = f2bf_rne(af[8 + e] - bf2f(hb));
        }

        __syncthreads();
        *(short8*)lds_pt(Ah, srow, ssl)     = ah0.v;
        *(short8*)lds_pt(Ah, srow, ssl | 1) = ah1.v;
        *(short8*)lds_pt(Al, srow, ssl)     = al0.v;
        *(short8*)lds_pt(Al, srow, ssl | 1) = al1.v;
        if (bstage) {
            *(short8*)lds_pt(Bh, srow, ssl)     = pb0;
            *(short8*)lds_pt(Bh, srow, ssl | 1) = pb1;
            *(short8*)lds_pt(Bl, srow, ssl)     = pb2;
            *(short8*)lds_pt(Bl, srow, ssl | 1) = pb3;
        }
        __syncthreads();

        short8 a_h[4], a_l[4], b_h[2], b_l[2];
#pragma unroll
        for (int i = 0; i < 4; ++i) {
            a_h[i] = *(const short8*)lds_pt(Ah, wm + i * 16 + m16, quad);
            a_l[i] = *(const short8*)lds_pt(Al, wm + i * 16 + m16, quad);
        }
#pragma unroll
        for (int j = 0; j < 2; ++j) {
            b_h[j] = *(const short8*)lds_pt(Bh, wn + j * 16 + m16, quad);
            b_l[j] = *(const short8*)lds_pt(Bl, wn + j * 16 + m16, quad);
        }
#pragma unroll
        for (int i = 0; i < 4; ++i)
#pragma unroll
            for (int j = 0; j < 2; ++j) {
                acc[i][j] = __builtin_amdgcn_mfma_f32_16x16x32_bf16(
                    a_h[i], b_h[j], acc[i][j], 0, 0, 0);
                acc[i][j] = __builtin_amdgcn_mfma_f32_16x16x32_bf16(
                    a_l[i], b_h[j], acc[i][j], 0, 0, 0);
                acc[i][j] = __builtin_amdgcn_mfma_f32_16x16x32_bf16(
                    a_h[i], b_l[j], acc[i][j], 0, 0, 0);
            }
    }

#pragma unroll
    for (int i = 0; i < 4; ++i)
#pragma unroll
        for (int j = 0; j < 2; ++j) {
            const int col = wn + j * 16 + m16;
#pragma unroll
            for (int r = 0; r < 4; ++r) {
                const int row = m0 + wm + i * 16 + quad * 4 + r;
                C[(size_t)row * ldc + col] = acc[i][j][r];
            }
        }
}

// ---------------- conv halo save: raw x at split boundaries --------------------
__global__ __launch_bounds__(256)
void halo_save(const float* __restrict__ xs, float* __restrict__ halo) {
    const int idx = blockIdx.x * 256 + threadIdx.x;  // NBC*(CSPL-1)*3*DINNER
    if (idx >= NBC * (CSPL - 1) * 3 * DINNER) return;
    const int d  = idx & (DINNER - 1);
    int r = idx >> 10;                   // 0 .. 32*7*3-1
    const int j  = r % 3;  r /= 3;       // halo element 0..2
    const int sp = (r % (CSPL - 1)) + 1; // split 1..7
    const int b  = r / (CSPL - 1);
    halo[(((size_t)b * CSPL + sp) * 3 + j) * DINNER + d] =
        xs[((size_t)b * SEQ + sp * CTS - 3 + j) * DINNER + d];
}

// ---------------- depthwise causal conv (w=4) + bias + SiLU, in place, split ---
__global__ __launch_bounds__(256)
void conv_split_silu(float* __restrict__ xs,
                     const float* __restrict__ conv_w,
                     const float* __restrict__ conv_b,
                     const float* __restrict__ halo) {
    const int gid = blockIdx.x * 256 + threadIdx.x;  // NBC*CSPL*DINNER threads
    const int d  = gid & (DINNER - 1);
    const int sp = (gid >> 10) & (CSPL - 1);
    const int b  = gid >> 13;
    const float w0 = conv_w[d * DCONV + 0];
    const float w1 = conv_w[d * DCONV + 1];
    const float w2 = conv_w[d * DCONV + 2];
    const float w3 = conv_w[d * DCONV + 3];
    const float cb = conv_b[d];
    float x0, x1, x2;
    if (sp == 0) {
        x0 = 0.0f; x1 = 0.0f; x2 = 0.0f;
    } else {
        const float* hsrc = halo + (((size_t)b * CSPL + sp) * 3) * DINNER + d;
        x0 = hsrc[0];
        x1 = hsrc[DINNER];
        x2 = hsrc[2 * DINNER];
    }
    size_t p = ((size_t)b * SEQ + sp * CTS) * DINNER + d;
    for (int t = 0; t < CTS; ++t, p += DINNER) {
        const float xv = xs[p];
        const float acc = cb + w0 * x0 + w1 * x1 + w2 * x2 + w3 * xv;
        xs[p] = siluf(acc);
        x0 = x1; x1 = x2; x2 = xv;
    }
}

// ---------------- chunked selective scan (2 passes, write-once scratch) --------
// Verified round-10/12 structure (180 us/pass): x_dbl rows read DIRECTLY from
// global via wave-uniform pointers -> hipcc scalarizes to s_load through the
// scalar cache (LDS 0, no barriers). Power-tree dA, a-array elided,
// group-of-8 xs prefetch.
__device__ __forceinline__ size_t ps_idx(int c, int b, int slot, int d) {
    return ((size_t)(c * NBC + b) * PSLOT + slot) * DINNER + d;
}

template <int PASS>
__global__ __launch_bounds__(256)
void scan_chunk_kernel(float* __restrict__ xs,        // in: conv'd x; out(P1): y+x*D
                       const float* __restrict__ x_dbl,
                       const float* __restrict__ W_dt,
                       const float* __restrict__ b_dt,
                       const float* __restrict__ A_log,
                       const float* __restrict__ Dp,
                       float* __restrict__ ps) {
    const int tid = threadIdx.x;
    const int c  = blockIdx.x & (GCH - 1);
    const int dg = (blockIdx.x >> 4) & 3;
    const int b  = blockIdx.x >> 6;
    const int d  = (dg << 8) + tid;

    // Chunk GCH-1's (dtsum,S) is never consumed (PASS1 reads only j < c).
    if (PASS == 0 && c == GCH - 1) return;

    float wdt[DTRANK];
#pragma unroll
    for (int k = 0; k < DTRANK; ++k) wdt[k] = W_dt[d * DTRANK + k];
    const float bdt = b_dt[d];
    const float Dv = Dp[d];

    const float a0 = -expf(A_log[d * DSTATE]);
    bool afast = true;
#pragma unroll
    for (int s = 0; s < DSTATE; ++s) {
        const float as = -expf(A_log[d * DSTATE + s]);   // transient
        afast = afast && (fabsf(as + (float)(s + 1)) <= 3e-3f * (float)(s + 1));
    }

    float h[DSTATE];
    float dtsum = 0.0f;
#pragma unroll
    for (int s = 0; s < DSTATE; ++s) h[s] = 0.0f;

    if (PASS == 1) {
        // Fused chunk prefix: h_in = compose(chunks 0..c-1).
        for (int j = 0; j < c; ++j) {       // wave-uniform trip count
            const float dsj = ps[ps_idx(j, b, 0, d)];
            if (afast) {
                const float F  = __expf(dsj * a0);
                const float F2 = F * F;
                const float F3 = F2 * F;
                const float F4 = F2 * F2;
                const float F8 = F4 * F4;
                const float F12 = F8 * F4;
#pragma unroll
                for (int s = 0; s < DSTATE; ++s) {
                    const float p = ((s & 3) == 0) ? F : ((s & 3) == 1) ? F2
                                  : ((s & 3) == 2) ? F3 : F4;
                    const float base = (s < 4) ? 1.0f : (s < 8) ? F4
                                     : (s < 12) ? F8 : F12;
                    const float P = (s < 4) ? p : base * p;
                    h[s] = fmaf(P, h[s], ps[ps_idx(j, b, 1 + s, d)]);
                }
            } else {                          // cold exact path (never taken)
#pragma unroll
                for (int s = 0; s < DSTATE; ++s) {
                    const float as = -expf(A_log[d * DSTATE + s]);
                    h[s] = fmaf(__expf(dsj * as), h[s],
                                ps[ps_idx(j, b, 1 + s, d)]);
                }
            }
        }
    }

    const size_t brow = (size_t)b * SEQ + (size_t)c * CLEN;

    for (int gg = 0; gg < CLEN / 8; ++gg) {
        // 8 independent xs loads up front (pipeline, not serial-dependent)
        float xr[8];
        {
            const float* xp = xs + (brow + gg * 8) * DINNER + d;
#pragma unroll
            for (int e = 0; e < 8; ++e) xr[e] = xp[(size_t)e * DINNER];
        }
        float* xw = xs + (brow + gg * 8) * DINNER + d;

#pragma unroll
        for (int t8 = 0; t8 < 8; ++t8) {
            // wave-uniform row pointer -> compiler emits s_load (scalar path)
            const float* __restrict__ rr = x_dbl + (brow + gg * 8 + t8) * XD;

            // dt GEMV: SGPR operand x VGPR wdt, 4 indep fma chains
            float g0 = 0.0f, g1 = 0.0f, g2 = 0.0f, g3 = 0.0f;
#pragma unroll
            for (int k = 0; k < DTRANK; k += 4) {
                g0 = fmaf(rr[k + 0], wdt[k + 0], g0);
                g1 = fmaf(rr[k + 1], wdt[k + 1], g1);
                g2 = fmaf(rr[k + 2], wdt[k + 2], g2);
                g3 = fmaf(rr[k + 3], wdt[k + 3], g3);
            }
            const float dtv = softplus_fast(bdt + ((g0 + g1) + (g2 + g3)));
            if (PASS == 0) dtsum += dtv;

            // hoist uniform B/C scalars BEFORE the divergent afast branch
            float Bu[DSTATE], Cu[DSTATE];
#pragma unroll
            for (int s = 0; s < DSTATE; ++s) Bu[s] = rr[DTRANK + s];
            if (PASS == 1) {
#pragma unroll
                for (int s = 0; s < DSTATE; ++s) Cu[s] = rr[DTRANK + DSTATE + s];
            }

            const float xv = xr[t8];
            const float pre = dtv * xv;
            float y0 = 0.0f, y1 = 0.0f;
            if (afast) {
                // dA[s] = E^(s+1) via depth-4 power tree (not 16-deep chain)
                const float E   = __expf(dtv * a0);
                const float E2  = E * E;
                const float E3  = E2 * E;
                const float E4  = E2 * E2;
                const float E8  = E4 * E4;
                const float E12 = E8 * E4;
#pragma unroll
                for (int s = 0; s < DSTATE; ++s) {
                    const float p = ((s & 3) == 0) ? E : ((s & 3) == 1) ? E2
                                  : ((s & 3) == 2) ? E3 : E4;
                    const float base = (s < 4) ? 1.0f : (s < 8) ? E4
                                     : (s < 12) ? E8 : E12;
                    const float dA = (s < 4) ? p : base * p;
                    h[s] = fmaf(dA, h[s], pre * Bu[s]);
                    if (PASS == 1) {
                        if (s & 1) y1 = fmaf(h[s], Cu[s], y1);
                        else       y0 = fmaf(h[s], Cu[s], y0);
                    }
                }
            } else {                          // cold exact path (never taken)
#pragma unroll
                for (int s = 0; s < DSTATE; ++s) {
                    const float as = -expf(A_log[d * DSTATE + s]);
                    const float dA = __expf(dtv * as);
                    h[s] = fmaf(dA, h[s], pre * Bu[s]);
                    if (PASS == 1) {
                        if (s & 1) y1 = fmaf(h[s], Cu[s], y1);
                        else       y0 = fmaf(h[s], Cu[s], y0);
                    }
                }
            }
            if (PASS == 1) xw[(size_t)t8 * DINNER] = fmaf(xv, Dv, y0 + y1);
        }
    }

    if (PASS == 0) {
        ps[ps_idx(c, b, 0, d)] = dtsum;
#pragma unroll
        for (int s = 0; s < DSTATE; ++s)
            ps[ps_idx(c, b, 1 + s, d)] = h[s];
    }
}

// ---------------- launch ----------------
// Workspace ws: xs = 128 MiB (in-place pipeline, ends packed hi/lo bf16);
// optional tails (checked vs ws_size, graceful fallback):
//   [128, 130 MiB)  w2out  pre-split W_out
//   [130, 194 MiB)  x2     pre-split x (removes ALL conversion VALU in 1 & 5)
// d_out (64 MiB) doubles as scratch before the final GEMM:
//   [ 0,  8 MiB)  x_dbl    [ 8, ~44 MiB)  ps    [44, 48 MiB)  W2in
//   [48, 51 MiB)  halo     [52, 52.25 MiB) wxp2 (pre-split W_xproj)
// Step 6 overwrites all of d_out; everything it reads lives in ws / d_in.
// Every scratch region is fully rewritten each launch (graph-replay safe).
extern "C" void kernel_launch(void* const* d_in, const int* in_sizes, int n_in,
                              void* d_out, int out_size, void* d_ws, size_t ws_size,
                              hipStream_t stream) {
    const float* x       = (const float*)d_in[0];
    const float* W_in    = (const float*)d_in[1];
    const float* conv_w  = (const float*)d_in[2];
    const float* conv_b  = (const float*)d_in[3];
    const float* W_xproj = (const float*)d_in[4];
    const float* W_dt    = (const float*)d_in[5];
    const float* b_dt    = (const float*)d_in[6];
    const float* A_log   = (const float*)d_in[7];
    const float* Dp      = (const float*)d_in[8];
    const float* W_out   = (const float*)d_in[9];
    float* out = (float*)d_out;

    float* xs    = (float*)d_ws;             // in-place pipeline buffer
    float* x_dbl = out;                      // d_out[0 .. 2M floats)
    float* ps    = out + (size_t)NROWS * XD; // d_out[2M .. 10.91M floats)
    unsigned char* w2in = (unsigned char*)(out + 11534336);  // 44 MiB offset
    float* halo  = out + 12582912;                           // 48 MiB offset
    unsigned char* wxp2 = (unsigned char*)(out + 13631488);  // 52 MiB offset

    const size_t xs_bytes   = (size_t)NROWS * DINNER * 4;    // 128 MiB
    const size_t wout_bytes = (size_t)DMODEL * (DINNER / 32) * 128;  // 2 MiB
    const size_t x2_bytes   = (size_t)NROWS * (DMODEL / 32) * 128;   // 64 MiB
    unsigned char* w2out = (unsigned char*)d_ws + xs_bytes;
    unsigned char* x2    = (unsigned char*)d_ws + xs_bytes + wout_bytes;
    const bool have_wout = ws_size >= xs_bytes + wout_bytes;
    const bool have_x2   = ws_size >= xs_bytes + wout_bytes + x2_bytes;

    dim3 blk(256);

    // 0. prepasses: split weights (and x, if ws permits) -> blocked bf16 hi/lo
    split_w<<<(2048 * 16) / 256, blk, 0, stream>>>(W_in, w2in, 2048, DMODEL);
    split_w<<<(64 * 32 + 255) / 256, blk, 0, stream>>>(W_xproj, wxp2, XD, DINNER);
    if (have_wout)
        split_w<<<(512 * 32) / 256, blk, 0, stream>>>(W_out, w2out, DMODEL, DINNER);
    if (have_x2)
        split_w<<<(NROWS * 16) / 256, blk, 0, stream>>>(x, x2, NROWS, DMODEL);

    // 1. xs = u @ W_in[0:1024]^T   (M=32768, N=1024, K=512)
    if (have_x2)
        gemm_split<true, true, EPI_NONE><<<dim3(DINNER / 128, NROWS / 128), blk, 0, stream>>>(
            nullptr, x2, 0, nullptr, w2in, 0, xs, DINNER, DMODEL);
    else
        gemm_split<false, true, EPI_NONE><<<dim3(DINNER / 128, NROWS / 128), blk, 0, stream>>>(
            x, nullptr, DMODEL, nullptr, w2in, 0, xs, DINNER, DMODEL);

    // 2a. save raw x at conv split boundaries (before any conv write)
    halo_save<<<(NBC * (CSPL - 1) * 3 * DINNER) / 256, blk, 0, stream>>>(xs, halo);
    // 2b. depthwise conv + bias + SiLU, in place, t-split 8x
    conv_split_silu<<<NBC * CSPL * DINNER / 256, blk, 0, stream>>>(
        xs, conv_w, conv_b, halo);

    // 3. x_dbl = xs @ W_xproj^T    (M=32768, N=64, K=1024)  [MFMA, B pre-split]
    gemm_xproj<<<NROWS / 128, blk, 0, stream>>>(xs, DINNER, wxp2, x_dbl, XD, DINNER);

    // 4a. chunk-local (dtsum, S) -> ps (write-once; chunk GCH-1 early-exits)
    scan_chunk_kernel<0><<<NBC * 4 * GCH, blk, 0, stream>>>(
        xs, x_dbl, W_dt, b_dt, A_log, Dp, ps);
    // 4b. fused prefix + re-walk chunks, write ungated y + x*D over xs
    scan_chunk_kernel<1><<<NBC * 4 * GCH, blk, 0, stream>>>(
        xs, x_dbl, W_dt, b_dt, A_log, Dp, ps);

    // 5. z-gate + PACK: z = u @ W_in[1024:2048]^T; xs <- blocked hi/lo bf16 of
    //    y*silu(z), in place (consumed by step 6's A_PRE staging)
    if (have_x2)
        gemm_split<true, true, EPI_GATE_PACK><<<dim3(DINNER / 128, NROWS / 128), blk, 0, stream>>>(
            nullptr, x2, 0, nullptr, w2in + (size_t)1024 * 16 * 128, 0, xs, DINNER, DMODEL);
    else
        gemm_split<false, true, EPI_GATE_PACK><<<dim3(DINNER / 128, NROWS / 128), blk, 0, stream>>>(
            x, nullptr, DMODEL, nullptr, w2in + (size_t)1024 * 16 * 128, 0, xs, DINNER, DMODEL);

    // 6. out = y2 @ W_out^T        (M=32768, N=512, K=1024)  [A pre-split]
    if (have_wout)
        gemm_split<true, true, EPI_NONE><<<dim3(DMODEL / 128, NROWS / 128), blk, 0, stream>>>(
            nullptr, (const unsigned char*)xs, 0, nullptr, w2out, 0, out, DMODEL, DINNER);
    else
        gemm_split<true, false, EPI_NONE><<<dim3(DMODEL / 128, NROWS / 128), blk, 0, stream>>>(
            nullptr, (const unsigned char*)xs, 0, W_out, nullptr, DINNER, out, DMODEL, DINNER);
}

// Round 14
// 797.673 us; speedup vs baseline: 1.2858x; 1.2858x over previous
//
#include <hip/hip_runtime.h>
#include <hip/hip_bf16.h>
#include <math.h>

// Problem dims (fixed)
#define BATCHN   4
#define CHN      8
#define SEQ      1024
#define DMODEL   512
#define DSTATE   16
#define DCONV    4
#define DINNER   1024
#define DTRANK   32
#define NROWS    32768          // BATCH*CH*SEQ
#define XD       64             // DT_RANK + 2*D_STATE
#define NBC      32             // BATCH*CH (independent sequences)
#define NXCD     8              // MI355X XCD count

// Scan chunking
#define GCH   16                // chunks per sequence
#define CLEN  (SEQ / GCH)       // 64 timesteps per chunk
#define PSLOT 17                // ps slots per (chunk,b,d): [dtsum | S x16]

// Conv splitting
#define CSPL  8                 // t-splits per sequence
#define CTS   (SEQ / CSPL)      // 128 timesteps per split

enum { EPI_NONE = 0, EPI_GATE = 1, EPI_GATE_PACK = 2 };

__device__ __forceinline__ float siluf(float v) {
    return v / (1.0f + __expf(-v));   // hw v_exp (~3 ops) vs library expf (~25)
}
__device__ __forceinline__ float softplus_fast(float v) {
    return (v > 20.0f) ? v : __logf(1.0f + __expf(v));
}

typedef short short8 __attribute__((ext_vector_type(8)));
typedef float floatx4 __attribute__((ext_vector_type(4)));

__device__ __forceinline__ unsigned short f2bf_rne(float f) {
    unsigned int u = __float_as_uint(f);
    u += 0x7fffu + ((u >> 16) & 1u);
    return (unsigned short)(u >> 16);
}
__device__ __forceinline__ float bf2f(unsigned short h) {
    return __uint_as_float(((unsigned int)h) << 16);
}

// LDS tile addressing: rows of 32 shorts (64 B), 4 x 16-B slots per row,
// slot XOR-swizzled by (row>>1)&3. Same mapping on store and read ->
// bit-identical data; fragment reads spread across all 32 banks 2-way (free).
__device__ __forceinline__ unsigned short* lds_pt(unsigned short (*arr)[32],
                                                  int row, int slot) {
    return &arr[row][(slot ^ ((row >> 1) & 3)) << 3];
}
__device__ __forceinline__ const unsigned short* lds_pt(
        const unsigned short (*arr)[32], int row, int slot) {
    return &arr[row][(slot ^ ((row >> 1) & 3)) << 3];
}

// ---------------- prepass: f32 [R][K] -> blocked split bf16 --------------------
// Per (row, kblock of 32 k's): 128 B = [32 x hi bf16 | 32 x lo bf16], linear.
// hi+lo pairs are bit-identical to the GEMM's on-the-fly split (same f2bf_rne).
__global__ __launch_bounds__(256)
void split_w(const float* __restrict__ W, unsigned char* __restrict__ W2,
             int R, int K) {
    const int KB = K >> 5;
    const int idx = blockIdx.x * 256 + threadIdx.x;   // one per (row, kblock)
    if (idx >= R * KB) return;
    const int row = idx / KB;
    const int kb  = idx - row * KB;
    const float* src = W + (size_t)row * K + kb * 32;
    unsigned short h[32], l[32];
#pragma unroll
    for (int e = 0; e < 32; e += 4) {
        const float4 v = *(const float4*)(src + e);
        const float vv[4] = {v.x, v.y, v.z, v.w};
#pragma unroll
        for (int q = 0; q < 4; ++q) {
            const unsigned short hi = f2bf_rne(vv[q]);
            h[e + q] = hi;
            l[e + q] = f2bf_rne(vv[q] - bf2f(hi));
        }
    }
    unsigned char* dst = W2 + ((size_t)row * KB + kb) * 128;
    union { short8 v; unsigned short u[8]; } pk;
#pragma unroll
    for (int c = 0; c < 4; ++c) {           // hi bytes [0,64)
#pragma unroll
        for (int e = 0; e < 8; ++e) pk.u[e] = h[c * 8 + e];
        *(short8*)(dst + c * 16) = pk.v;
    }
#pragma unroll
    for (int c = 0; c < 4; ++c) {           // lo bytes [64,128)
#pragma unroll
        for (int e = 0; e < 8; ++e) pk.u[e] = l[c * 8 + e];
        *(short8*)(dst + 64 + c * 16) = pk.v;
    }
}

// ---------------- bf16-split MFMA GEMM: C[M,N] = A[M,K] * B[N,K]^T --------------
// 3-term split product hi*hi + lo*hi + hi*lo in fp32 accumulators (~2^-17 rel).
// BK=32 (r13's BK=64 regressed: 204 vs <=180 us -- bigger LDS hurt latency
// hiding, barriers were NOT the bottleneck). r13 counters showed the GEMM is
// HBM-traffic-bound (FETCH 335 MB, VALUBusy 18%): each A-panel is re-fetched
// by every n-block into a DIFFERENT XCD's L2 under round-robin dispatch.
// FIX 1: bijective XCD-aware block swizzle (logical = (hw%8)*(nwg/8)+hw/8) --
//   consecutive logical blocks share one A-panel, each XCD streams contiguous
//   panels -> each panel hits HBM once. Requires nwg%8==0 (2048/2048/1024 OK).
// FIX 2: __launch_bounds__(256,4): 32 KiB LDS fits 4 blocks/CU; VGPR 88<=128.
// A_PRE / B_PRE: operand pre-split blocked bf16 -> staging is pure short8
// load + LDS store, zero conversion VALU. Otherwise f32 split on the fly.
// EPI_GATE:      C = C_old * silu(acc)  (f32 write)
// EPI_GATE_PACK: g = C_old * silu(acc); write g as blocked hi/lo bf16 IN PLACE
//   over C. Safe: each 128-B block read+written by exactly one wave quad;
//   reads hoisted per row-group + vmcnt(0) fence before stores.
template <bool A_PRE, bool B_PRE, int EPI>
__global__ __launch_bounds__(256, 4)
void gemm_split(const float* __restrict__ Af, const unsigned char* __restrict__ A2,
                int lda,
                const float* __restrict__ Bf, const unsigned char* __restrict__ B2,
                int ldb,
                float* __restrict__ C, int ldc,
                int K) {
    __shared__ __align__(16) unsigned short Ah[128][32];
    __shared__ __align__(16) unsigned short Al[128][32];
    __shared__ __align__(16) unsigned short Bh[128][32];
    __shared__ __align__(16) unsigned short Bl[128][32];

    const int tid  = threadIdx.x;
    const int lane = tid & 63;
    const int wv   = tid >> 6;
    const int quad = lane >> 4;
    const int m16  = lane & 15;
    const int wm   = (wv & 1) * 64;       // wave's m-offset in block tile
    const int wn   = (wv >> 1) * 64;      // wave's n-offset

    // XCD-aware bijective swizzle: hw round-robins over XCDs; give XCD k the
    // contiguous logical range [k*nwg/8, (k+1)*nwg/8). Logical ids walk
    // n-blocks fastest -> blocks sharing an A-panel stay on one XCD/L2.
    const int nwg  = gridDim.x * gridDim.y;
    const int hw   = blockIdx.y * gridDim.x + blockIdx.x;
    const int cpx  = nwg / NXCD;          // nwg % 8 == 0 for all call sites
    const int lgc  = (hw % NXCD) * cpx + hw / NXCD;
    const int m0   = (lgc / gridDim.x) * 128;
    const int n0   = (lgc % gridDim.x) * 128;

    const int srow = tid >> 1;            // staging row 0..127
    const int skb  = (tid & 1) * 16;      // staging k-offset 0 / 16 (shorts)
    const int ssl  = skb >> 3;            // staging slot 0 / 2

    const unsigned char* aptr = nullptr;
    const unsigned char* bptr = nullptr;
    if constexpr (A_PRE)
        aptr = A2 + (size_t)(m0 + srow) * (K >> 5) * 128 + 2 * skb;
    if constexpr (B_PRE)
        bptr = B2 + (size_t)(n0 + srow) * (K >> 5) * 128 + 2 * skb;

    floatx4 acc[4][4];
#pragma unroll
    for (int i = 0; i < 4; ++i)
#pragma unroll
        for (int j = 0; j < 4; ++j) acc[i][j] = (floatx4){0.f, 0.f, 0.f, 0.f};

    union U { short8 v; unsigned short u[8]; };

    for (int k0 = 0; k0 < K; k0 += 32) {
        short8 pa0, pa1, pa2, pa3;         // A_PRE path
        U ah0, ah1, al0, al1;              // !A_PRE path
        if constexpr (A_PRE) {
            pa0 = *(const short8*)(aptr);        // hi, k [skb, skb+8)
            pa1 = *(const short8*)(aptr + 16);   // hi, k [skb+8, skb+16)
            pa2 = *(const short8*)(aptr + 64);   // lo
            pa3 = *(const short8*)(aptr + 80);
            aptr += 128;
        } else {
            const float* ap = Af + (size_t)(m0 + srow) * lda + k0 + skb;
            const float4 a0 = *(const float4*)(ap + 0);
            const float4 a1 = *(const float4*)(ap + 4);
            const float4 a2 = *(const float4*)(ap + 8);
            const float4 a3 = *(const float4*)(ap + 12);
            const float af[16] = {a0.x, a0.y, a0.z, a0.w, a1.x, a1.y, a1.z, a1.w,
                                  a2.x, a2.y, a2.z, a2.w, a3.x, a3.y, a3.z, a3.w};
#pragma unroll
            for (int e = 0; e < 8; ++e) {
                const unsigned short ha = f2bf_rne(af[e]);
                ah0.u[e] = ha; al0.u[e] = f2bf_rne(af[e] - bf2f(ha));
                const unsigned short hb = f2bf_rne(af[8 + e]);
                ah1.u[e] = hb; al1.u[e] = f2bf_rne(af[8 + e] - bf2f(hb));
            }
        }

        short8 pb0, pb1, pb2, pb3;         // B_PRE path
        U bh0, bh1, bl0, bl1;              // !B_PRE path
        if constexpr (B_PRE) {
            pb0 = *(const short8*)(bptr);
            pb1 = *(const short8*)(bptr + 16);
            pb2 = *(const short8*)(bptr + 64);
            pb3 = *(const short8*)(bptr + 80);
            bptr += 128;
        } else {
            const float* bp = Bf + (size_t)(n0 + srow) * ldb + k0 + skb;
            const float4 b0 = *(const float4*)(bp + 0);
            const float4 b1 = *(const float4*)(bp + 4);
            const float4 b2 = *(const float4*)(bp + 8);
            const float4 b3 = *(const float4*)(bp + 12);
            const float bf[16] = {b0.x, b0.y, b0.z, b0.w, b1.x, b1.y, b1.z, b1.w,
                                  b2.x, b2.y, b2.z, b2.w, b3.x, b3.y, b3.z, b3.w};
#pragma unroll
            for (int e = 0; e < 8; ++e) {
                const unsigned short ha = f2bf_rne(bf[e]);
                bh0.u[e] = ha; bl0.u[e] = f2bf_rne(bf[e] - bf2f(ha));
                const unsigned short hb = f2bf_rne(bf[8 + e]);
                bh1.u[e] = hb; bl1.u[e] = f2bf_rne(bf[8 + e] - bf2f(hb));
            }
        }

        __syncthreads();   // all waves done reading previous tile
        if constexpr (A_PRE) {
            *(short8*)lds_pt(Ah, srow, ssl)     = pa0;
            *(short8*)lds_pt(Ah, srow, ssl | 1) = pa1;
            *(short8*)lds_pt(Al, srow, ssl)     = pa2;
            *(short8*)lds_pt(Al, srow, ssl | 1) = pa3;
        } else {
            *(short8*)lds_pt(Ah, srow, ssl)     = ah0.v;
            *(short8*)lds_pt(Ah, srow, ssl | 1) = ah1.v;
            *(short8*)lds_pt(Al, srow, ssl)     = al0.v;
            *(short8*)lds_pt(Al, srow, ssl | 1) = al1.v;
        }
        if constexpr (B_PRE) {
            *(short8*)lds_pt(Bh, srow, ssl)     = pb0;
            *(short8*)lds_pt(Bh, srow, ssl | 1) = pb1;
            *(short8*)lds_pt(Bl, srow, ssl)     = pb2;
            *(short8*)lds_pt(Bl, srow, ssl | 1) = pb3;
        } else {
            *(short8*)lds_pt(Bh, srow, ssl)     = bh0.v;
            *(short8*)lds_pt(Bh, srow, ssl | 1) = bh1.v;
            *(short8*)lds_pt(Bl, srow, ssl)     = bl0.v;
            *(short8*)lds_pt(Bl, srow, ssl | 1) = bl1.v;
        }
        __syncthreads();

        short8 a_h[4], a_l[4], b_h[4], b_l[4];
#pragma unroll
        for (int i = 0; i < 4; ++i) {
            a_h[i] = *(const short8*)lds_pt(Ah, wm + i * 16 + m16, quad);
            a_l[i] = *(const short8*)lds_pt(Al, wm + i * 16 + m16, quad);
            b_h[i] = *(const short8*)lds_pt(Bh, wn + i * 16 + m16, quad);
            b_l[i] = *(const short8*)lds_pt(Bl, wn + i * 16 + m16, quad);
        }
#pragma unroll
        for (int i = 0; i < 4; ++i)
#pragma unroll
            for (int j = 0; j < 4; ++j) {
                acc[i][j] = __builtin_amdgcn_mfma_f32_16x16x32_bf16(
                    a_h[i], b_h[j], acc[i][j], 0, 0, 0);
                acc[i][j] = __builtin_amdgcn_mfma_f32_16x16x32_bf16(
                    a_l[i], b_h[j], acc[i][j], 0, 0, 0);
                acc[i][j] = __builtin_amdgcn_mfma_f32_16x16x32_bf16(
                    a_h[i], b_l[j], acc[i][j], 0, 0, 0);
            }
    }

    // Epilogue. C/D layout: col = lane&15, row = quad*4 + reg [m89/m91 verified]
    if constexpr (EPI != EPI_GATE_PACK) {
#pragma unroll
        for (int i = 0; i < 4; ++i)
#pragma unroll
            for (int j = 0; j < 4; ++j) {
                const int col = n0 + wn + j * 16 + m16;
#pragma unroll
                for (int r = 0; r < 4; ++r) {
                    const int row = m0 + wm + i * 16 + quad * 4 + r;
                    const size_t off = (size_t)row * ldc + col;
                    const float v = acc[i][j][r];
                    if (EPI == EPI_NONE) C[off] = v;
                    else                 C[off] = C[off] * siluf(v);
                }
            }
    } else {   // EPI_GATE_PACK: in-place f32 -> gated blocked hi/lo bf16
        unsigned char* Y2 = (unsigned char*)C;
        const size_t rowbytes = (size_t)ldc * 4;   // == (ldc/32)*128
#pragma unroll
        for (int i = 0; i < 4; ++i) {
            const int rbase = m0 + wm + i * 16 + quad * 4;
            float cold[4][4];
#pragma unroll
            for (int j = 0; j < 4; ++j) {
                const int col = n0 + wn + j * 16 + m16;
#pragma unroll
                for (int r = 0; r < 4; ++r)
                    cold[j][r] = C[(size_t)(rbase + r) * ldc + col];
            }
            // all reads of this row-group land before any byte is overwritten
            asm volatile("s_waitcnt vmcnt(0)" ::: "memory");
#pragma unroll
            for (int j = 0; j < 4; ++j) {
                const int col = n0 + wn + j * 16 + m16;
                const int kb  = col >> 5;
                const unsigned off = (unsigned)(col & 31) * 2;
#pragma unroll
                for (int r = 0; r < 4; ++r) {
                    const int row = rbase + r;
                    const float g = cold[j][r] * siluf(acc[i][j][r]);
                    const unsigned short hi = f2bf_rne(g);
                    const unsigned short lo = f2bf_rne(g - bf2f(hi));
                    unsigned char* bp = Y2 + (size_t)row * rowbytes + (size_t)kb * 128;
                    *(unsigned short*)(bp + off)      = hi;
                    *(unsigned short*)(bp + 64 + off) = lo;
                }
            }
        }
    }
}

// ---------------- MFMA x-proj GEMM: C[M,64] = A[M,K] * B[64,K]^T ---------------
// Block tile 128x64, 4 waves (2x2), each wave 64x32 = 4x2 frags,
// 24 MFMA/wave/K-step. A = xs f32 split on the fly; B = W_xproj pre-split.
__global__ __launch_bounds__(256, 2)
void gemm_xproj(const float* __restrict__ A, int lda,
                const unsigned char* __restrict__ B2,
                float* __restrict__ C, int ldc,
                int K) {
    __shared__ __align__(16) unsigned short Ah[128][32];
    __shared__ __align__(16) unsigned short Al[128][32];
    __shared__ __align__(16) unsigned short Bh[64][32];
    __shared__ __align__(16) unsigned short Bl[64][32];

    const int tid  = threadIdx.x;
    const int lane = tid & 63;
    const int wv   = tid >> 6;
    const int quad = lane >> 4;
    const int m16  = lane & 15;
    const int wm   = (wv & 1) * 64;
    const int wn   = (wv >> 1) * 32;
    const int m0   = blockIdx.x * 128;

    const int srow = tid >> 1;            // A staging row 0..127
    const int skb  = (tid & 1) * 16;
    const int ssl  = skb >> 3;

    const unsigned char* bptr = B2 + (size_t)srow * (K >> 5) * 128 + 2 * skb;
    const bool bstage = tid < 128;        // rows 0..63 (waves 0,1 only)

    floatx4 acc[4][2];
#pragma unroll
    for (int i = 0; i < 4; ++i)
#pragma unroll
        for (int j = 0; j < 2; ++j) acc[i][j] = (floatx4){0.f, 0.f, 0.f, 0.f};

    union U { short8 v; unsigned short u[8]; };

    for (int k0 = 0; k0 < K; k0 += 32) {
        const float* ap = A + (size_t)(m0 + srow) * lda + k0 + skb;
        const float4 a0 = *(const float4*)(ap + 0);
        const float4 a1 = *(const float4*)(ap + 4);
        const float4 a2 = *(const float4*)(ap + 8);
        const float4 a3 = *(const float4*)(ap + 12);
        const float af[16] = {a0.x, a0.y, a0.z, a0.w, a1.x, a1.y, a1.z, a1.w,
                              a2.x, a2.y, a2.z, a2.w, a3.x, a3.y, a3.z, a3.w};
        short8 pb0, pb1, pb2, pb3;
        if (bstage) {
            pb0 = *(const short8*)(bptr);
            pb1 = *(const short8*)(bptr + 16);
            pb2 = *(const short8*)(bptr + 64);
            pb3 = *(const short8*)(bptr + 80);
        }
        bptr += 128;

        U ah0, ah1, al0, al1;
#pragma unroll
        for (int e = 0; e < 8; ++e) {
            const unsigned short ha = f2bf_rne(af[e]);
            ah0.u[e] = ha; al0.u[e] = f2bf_rne(af[e] - bf2f(ha));
            const unsigned short hb = f2bf_rne(af[8 + e]);
            ah1.u[e] = hb; al1.u[e] = f2bf_rne(af[8 + e] - bf2f(hb));
        }

        __syncthreads();
        *(short8*)lds_pt(Ah, srow, ssl)     = ah0.v;
        *(short8*)lds_pt(Ah, srow, ssl | 1) = ah1.v;
        *(short8*)lds_pt(Al, srow, ssl)     = al0.v;
        *(short8*)lds_pt(Al, srow, ssl | 1) = al1.v;
        if (bstage) {
            *(short8*)lds_pt(Bh, srow, ssl)     = pb0;
            *(short8*)lds_pt(Bh, srow, ssl | 1) = pb1;
            *(short8*)lds_pt(Bl, srow, ssl)     = pb2;
            *(short8*)lds_pt(Bl, srow, ssl | 1) = pb3;
        }
        __syncthreads();

        short8 a_h[4], a_l[4], b_h[2], b_l[2];
#pragma unroll
        for (int i = 0; i < 4; ++i) {
            a_h[i] = *(const short8*)lds_pt(Ah, wm + i * 16 + m16, quad);
            a_l[i] = *(const short8*)lds_pt(Al, wm + i * 16 + m16, quad);
        }
#pragma unroll
        for (int j = 0; j < 2; ++j) {
            b_h[j] = *(const short8*)lds_pt(Bh, wn + j * 16 + m16, quad);
            b_l[j] = *(const short8*)lds_pt(Bl, wn + j * 16 + m16, quad);
        }
#pragma unroll
        for (int i = 0; i < 4; ++i)
#pragma unroll
            for (int j = 0; j < 2; ++j) {
                acc[i][j] = __builtin_amdgcn_mfma_f32_16x16x32_bf16(
                    a_h[i], b_h[j], acc[i][j], 0, 0, 0);
                acc[i][j] = __builtin_amdgcn_mfma_f32_16x16x32_bf16(
                    a_l[i], b_h[j], acc[i][j], 0, 0, 0);
                acc[i][j] = __builtin_amdgcn_mfma_f32_16x16x32_bf16(
                    a_h[i], b_l[j], acc[i][j], 0, 0, 0);
            }
    }

#pragma unroll
    for (int i = 0; i < 4; ++i)
#pragma unroll
        for (int j = 0; j < 2; ++j) {
            const int col = wn + j * 16 + m16;
#pragma unroll
            for (int r = 0; r < 4; ++r) {
                const int row = m0 + wm + i * 16 + quad * 4 + r;
                C[(size_t)row * ldc + col] = acc[i][j][r];
            }
        }
}

// ---------------- conv halo save: raw x at split boundaries --------------------
__global__ __launch_bounds__(256)
void halo_save(const float* __restrict__ xs, float* __restrict__ halo) {
    const int idx = blockIdx.x * 256 + threadIdx.x;  // NBC*(CSPL-1)*3*DINNER
    if (idx >= NBC * (CSPL - 1) * 3 * DINNER) return;
    const int d  = idx & (DINNER - 1);
    int r = idx >> 10;                   // 0 .. 32*7*3-1
    const int j  = r % 3;  r /= 3;       // halo element 0..2
    const int sp = (r % (CSPL - 1)) + 1; // split 1..7
    const int b  = r / (CSPL - 1);
    halo[(((size_t)b * CSPL + sp) * 3 + j) * DINNER + d] =
        xs[((size_t)b * SEQ + sp * CTS - 3 + j) * DINNER + d];
}

// ---------------- depthwise causal conv (w=4) + bias + SiLU, in place, split ---
__global__ __launch_bounds__(256)
void conv_split_silu(float* __restrict__ xs,
                     const float* __restrict__ conv_w,
                     const float* __restrict__ conv_b,
                     const float* __restrict__ halo) {
    const int gid = blockIdx.x * 256 + threadIdx.x;  // NBC*CSPL*DINNER threads
    const int d  = gid & (DINNER - 1);
    const int sp = (gid >> 10) & (CSPL - 1);
    const int b  = gid >> 13;
    const float w0 = conv_w[d * DCONV + 0];
    const float w1 = conv_w[d * DCONV + 1];
    const float w2 = conv_w[d * DCONV + 2];
    const float w3 = conv_w[d * DCONV + 3];
    const float cb = conv_b[d];
    float x0, x1, x2;
    if (sp == 0) {
        x0 = 0.0f; x1 = 0.0f; x2 = 0.0f;
    } else {
        const float* hsrc = halo + (((size_t)b * CSPL + sp) * 3) * DINNER + d;
        x0 = hsrc[0];
        x1 = hsrc[DINNER];
        x2 = hsrc[2 * DINNER];
    }
    size_t p = ((size_t)b * SEQ + sp * CTS) * DINNER + d;
    for (int t = 0; t < CTS; ++t, p += DINNER) {
        const float xv = xs[p];
        const float acc = cb + w0 * x0 + w1 * x1 + w2 * x2 + w3 * xv;
        xs[p] = siluf(acc);
        x0 = x1; x1 = x2; x2 = xv;
    }
}

// ---------------- chunked selective scan (2 passes, write-once scratch) --------
// Verified round-10/12 structure (180 us/pass): x_dbl rows read DIRECTLY from
// global via wave-uniform pointers -> hipcc scalarizes to s_load through the
// scalar cache (LDS 0, no barriers). Power-tree dA, a-array elided,
// group-of-8 xs prefetch.
__device__ __forceinline__ size_t ps_idx(int c, int b, int slot, int d) {
    return ((size_t)(c * NBC + b) * PSLOT + slot) * DINNER + d;
}

template <int PASS>
__global__ __launch_bounds__(256)
void scan_chunk_kernel(float* __restrict__ xs,        // in: conv'd x; out(P1): y+x*D
                       const float* __restrict__ x_dbl,
                       const float* __restrict__ W_dt,
                       const float* __restrict__ b_dt,
                       const float* __restrict__ A_log,
                       const float* __restrict__ Dp,
                       float* __restrict__ ps) {
    const int tid = threadIdx.x;
    const int c  = blockIdx.x & (GCH - 1);
    const int dg = (blockIdx.x >> 4) & 3;
    const int b  = blockIdx.x >> 6;
    const int d  = (dg << 8) + tid;

    // Chunk GCH-1's (dtsum,S) is never consumed (PASS1 reads only j < c).
    if (PASS == 0 && c == GCH - 1) return;

    float wdt[DTRANK];
#pragma unroll
    for (int k = 0; k < DTRANK; ++k) wdt[k] = W_dt[d * DTRANK + k];
    const float bdt = b_dt[d];
    const float Dv = Dp[d];

    const float a0 = -expf(A_log[d * DSTATE]);
    bool afast = true;
#pragma unroll
    for (int s = 0; s < DSTATE; ++s) {
        const float as = -expf(A_log[d * DSTATE + s]);   // transient
        afast = afast && (fabsf(as + (float)(s + 1)) <= 3e-3f * (float)(s + 1));
    }

    float h[DSTATE];
    float dtsum = 0.0f;
#pragma unroll
    for (int s = 0; s < DSTATE; ++s) h[s] = 0.0f;

    if (PASS == 1) {
        // Fused chunk prefix: h_in = compose(chunks 0..c-1).
        for (int j = 0; j < c; ++j) {       // wave-uniform trip count
            const float dsj = ps[ps_idx(j, b, 0, d)];
            if (afast) {
                const float F  = __expf(dsj * a0);
                const float F2 = F * F;
                const float F3 = F2 * F;
                const float F4 = F2 * F2;
                const float F8 = F4 * F4;
                const float F12 = F8 * F4;
#pragma unroll
                for (int s = 0; s < DSTATE; ++s) {
                    const float p = ((s & 3) == 0) ? F : ((s & 3) == 1) ? F2
                                  : ((s & 3) == 2) ? F3 : F4;
                    const float base = (s < 4) ? 1.0f : (s < 8) ? F4
                                     : (s < 12) ? F8 : F12;
                    const float P = (s < 4) ? p : base * p;
                    h[s] = fmaf(P, h[s], ps[ps_idx(j, b, 1 + s, d)]);
                }
            } else {                          // cold exact path (never taken)
#pragma unroll
                for (int s = 0; s < DSTATE; ++s) {
                    const float as = -expf(A_log[d * DSTATE + s]);
                    h[s] = fmaf(__expf(dsj * as), h[s],
                                ps[ps_idx(j, b, 1 + s, d)]);
                }
            }
        }
    }

    const size_t brow = (size_t)b * SEQ + (size_t)c * CLEN;

    for (int gg = 0; gg < CLEN / 8; ++gg) {
        // 8 independent xs loads up front (pipeline, not serial-dependent)
        float xr[8];
        {
            const float* xp = xs + (brow + gg * 8) * DINNER + d;
#pragma unroll
            for (int e = 0; e < 8; ++e) xr[e] = xp[(size_t)e * DINNER];
        }
        float* xw = xs + (brow + gg * 8) * DINNER + d;

#pragma unroll
        for (int t8 = 0; t8 < 8; ++t8) {
            // wave-uniform row pointer -> compiler emits s_load (scalar path)
            const float* __restrict__ rr = x_dbl + (brow + gg * 8 + t8) * XD;

            // dt GEMV: SGPR operand x VGPR wdt, 4 indep fma chains
            float g0 = 0.0f, g1 = 0.0f, g2 = 0.0f, g3 = 0.0f;
#pragma unroll
            for (int k = 0; k < DTRANK; k += 4) {
                g0 = fmaf(rr[k + 0], wdt[k + 0], g0);
                g1 = fmaf(rr[k + 1], wdt[k + 1], g1);
                g2 = fmaf(rr[k + 2], wdt[k + 2], g2);
                g3 = fmaf(rr[k + 3], wdt[k + 3], g3);
            }
            const float dtv = softplus_fast(bdt + ((g0 + g1) + (g2 + g3)));
            if (PASS == 0) dtsum += dtv;

            // hoist uniform B/C scalars BEFORE the divergent afast branch
            float Bu[DSTATE], Cu[DSTATE];
#pragma unroll
            for (int s = 0; s < DSTATE; ++s) Bu[s] = rr[DTRANK + s];
            if (PASS == 1) {
#pragma unroll
                for (int s = 0; s < DSTATE; ++s) Cu[s] = rr[DTRANK + DSTATE + s];
            }

            const float xv = xr[t8];
            const float pre = dtv * xv;
            float y0 = 0.0f, y1 = 0.0f;
            if (afast) {
                // dA[s] = E^(s+1) via depth-4 power tree (not 16-deep chain)
                const float E   = __expf(dtv * a0);
                const float E2  = E * E;
                const float E3  = E2 * E;
                const float E4  = E2 * E2;
                const float E8  = E4 * E4;
                const float E12 = E8 * E4;
#pragma unroll
                for (int s = 0; s < DSTATE; ++s) {
                    const float p = ((s & 3) == 0) ? E : ((s & 3) == 1) ? E2
                                  : ((s & 3) == 2) ? E3 : E4;
                    const float base = (s < 4) ? 1.0f : (s < 8) ? E4
                                     : (s < 12) ? E8 : E12;
                    const float dA = (s < 4) ? p : base * p;
                    h[s] = fmaf(dA, h[s], pre * Bu[s]);
                    if (PASS == 1) {
                        if (s & 1) y1 = fmaf(h[s], Cu[s], y1);
                        else       y0 = fmaf(h[s], Cu[s], y0);
                    }
                }
            } else {                          // cold exact path (never taken)
#pragma unroll
                for (int s = 0; s < DSTATE; ++s) {
                    const float as = -expf(A_log[d * DSTATE + s]);
                    const float dA = __expf(dtv * as);
                    h[s] = fmaf(dA, h[s], pre * Bu[s]);
                    if (PASS == 1) {
                        if (s & 1) y1 = fmaf(h[s], Cu[s], y1);
                        else       y0 = fmaf(h[s], Cu[s], y0);
                    }
                }
            }
            if (PASS == 1) xw[(size_t)t8 * DINNER] = fmaf(xv, Dv, y0 + y1);
        }
    }

    if (PASS == 0) {
        ps[ps_idx(c, b, 0, d)] = dtsum;
#pragma unroll
        for (int s = 0; s < DSTATE; ++s)
            ps[ps_idx(c, b, 1 + s, d)] = h[s];
    }
}

// ---------------- launch ----------------
// Workspace ws: xs = 128 MiB (in-place pipeline, ends packed hi/lo bf16);
// optional tails (checked vs ws_size, graceful fallback):
//   [128, 130 MiB)  w2out  pre-split W_out
//   [130, 194 MiB)  x2     pre-split x (removes ALL conversion VALU in 1 & 5)
// d_out (64 MiB) doubles as scratch before the final GEMM:
//   [ 0,  8 MiB)  x_dbl    [ 8, ~44 MiB)  ps    [44, 48 MiB)  W2in
//   [48, 51 MiB)  halo     [52, 52.25 MiB) wxp2 (pre-split W_xproj)
// Step 6 overwrites all of d_out; everything it reads lives in ws / d_in.
// Every scratch region is fully rewritten each launch (graph-replay safe).
extern "C" void kernel_launch(void* const* d_in, const int* in_sizes, int n_in,
                              void* d_out, int out_size, void* d_ws, size_t ws_size,
                              hipStream_t stream) {
    const float* x       = (const float*)d_in[0];
    const float* W_in    = (const float*)d_in[1];
    const float* conv_w  = (const float*)d_in[2];
    const float* conv_b  = (const float*)d_in[3];
    const float* W_xproj = (const float*)d_in[4];
    const float* W_dt    = (const float*)d_in[5];
    const float* b_dt    = (const float*)d_in[6];
    const float* A_log   = (const float*)d_in[7];
    const float* Dp      = (const float*)d_in[8];
    const float* W_out   = (const float*)d_in[9];
    float* out = (float*)d_out;

    float* xs    = (float*)d_ws;             // in-place pipeline buffer
    float* x_dbl = out;                      // d_out[0 .. 2M floats)
    float* ps    = out + (size_t)NROWS * XD; // d_out[2M .. 10.91M floats)
    unsigned char* w2in = (unsigned char*)(out + 11534336);  // 44 MiB offset
    float* halo  = out + 12582912;                           // 48 MiB offset
    unsigned char* wxp2 = (unsigned char*)(out + 13631488);  // 52 MiB offset

    const size_t xs_bytes   = (size_t)NROWS * DINNER * 4;    // 128 MiB
    const size_t wout_bytes = (size_t)DMODEL * (DINNER / 32) * 128;  // 2 MiB
    const size_t x2_bytes   = (size_t)NROWS * (DMODEL / 32) * 128;   // 64 MiB
    unsigned char* w2out = (unsigned char*)d_ws + xs_bytes;
    unsigned char* x2    = (unsigned char*)d_ws + xs_bytes + wout_bytes;
    const bool have_wout = ws_size >= xs_bytes + wout_bytes;
    const bool have_x2   = ws_size >= xs_bytes + wout_bytes + x2_bytes;

    dim3 blk(256);

    // 0. prepasses: split weights (and x, if ws permits) -> blocked bf16 hi/lo
    split_w<<<(2048 * 16) / 256, blk, 0, stream>>>(W_in, w2in, 2048, DMODEL);
    split_w<<<(64 * 32 + 255) / 256, blk, 0, stream>>>(W_xproj, wxp2, XD, DINNER);
    if (have_wout)
        split_w<<<(512 * 32) / 256, blk, 0, stream>>>(W_out, w2out, DMODEL, DINNER);
    if (have_x2)
        split_w<<<(NROWS * 16) / 256, blk, 0, stream>>>(x, x2, NROWS, DMODEL);

    // 1. xs = u @ W_in[0:1024]^T   (M=32768, N=1024, K=512)
    if (have_x2)
        gemm_split<true, true, EPI_NONE><<<dim3(DINNER / 128, NROWS / 128), blk, 0, stream>>>(
            nullptr, x2, 0, nullptr, w2in, 0, xs, DINNER, DMODEL);
    else
        gemm_split<false, true, EPI_NONE><<<dim3(DINNER / 128, NROWS / 128), blk, 0, stream>>>(
            x, nullptr, DMODEL, nullptr, w2in, 0, xs, DINNER, DMODEL);

    // 2a. save raw x at conv split boundaries (before any conv write)
    halo_save<<<(NBC * (CSPL - 1) * 3 * DINNER) / 256, blk, 0, stream>>>(xs, halo);
    // 2b. depthwise conv + bias + SiLU, in place, t-split 8x
    conv_split_silu<<<NBC * CSPL * DINNER / 256, blk, 0, stream>>>(
        xs, conv_w, conv_b, halo);

    // 3. x_dbl = xs @ W_xproj^T    (M=32768, N=64, K=1024)  [MFMA, B pre-split]
    gemm_xproj<<<NROWS / 128, blk, 0, stream>>>(xs, DINNER, wxp2, x_dbl, XD, DINNER);

    // 4a. chunk-local (dtsum, S) -> ps (write-once; chunk GCH-1 early-exits)
    scan_chunk_kernel<0><<<NBC * 4 * GCH, blk, 0, stream>>>(
        xs, x_dbl, W_dt, b_dt, A_log, Dp, ps);
    // 4b. fused prefix + re-walk chunks, write ungated y + x*D over xs
    scan_chunk_kernel<1><<<NBC * 4 * GCH, blk, 0, stream>>>(
        xs, x_dbl, W_dt, b_dt, A_log, Dp, ps);

    // 5. z-gate + PACK: z = u @ W_in[1024:2048]^T; xs <- blocked hi/lo bf16 of
    //    y*silu(z), in place (consumed by step 6's A_PRE staging)
    if (have_x2)
        gemm_split<true, true, EPI_GATE_PACK><<<dim3(DINNER / 128, NROWS / 128), blk, 0, stream>>>(
            nullptr, x2, 0, nullptr, w2in + (size_t)1024 * 16 * 128, 0, xs, DINNER, DMODEL);
    else
        gemm_split<false, true, EPI_GATE_PACK><<<dim3(DINNER / 128, NROWS / 128), blk, 0, stream>>>(
            x, nullptr, DMODEL, nullptr, w2in + (size_t)1024 * 16 * 128, 0, xs, DINNER, DMODEL);

    // 6. out = y2 @ W_out^T        (M=32768, N=512, K=1024)  [A pre-split]
    if (have_wout)
        gemm_split<true, true, EPI_NONE><<<dim3(DMODEL / 128, NROWS / 128), blk, 0, stream>>>(
            nullptr, (const unsigned char*)xs, 0, nullptr, w2out, 0, out, DMODEL, DINNER);
    else
        gemm_split<true, false, EPI_NONE><<<dim3(DMODEL / 128, NROWS / 128), blk, 0, stream>>>(
            nullptr, (const unsigned char*)xs, 0, W_out, nullptr, DINNER, out, DMODEL, DINNER);
}